// Round 4
// baseline (223.477 us; speedup 1.0000x reference)
//
#include <hip/hip_runtime.h>
#include <cstddef>

// Problem constants (bs=16, T=50, A=3, H=W=76, C=80, stride 8)
#define NB 16
#define NT 50
#define NA 3
#define NH 76
#define NW 76
#define NC 80
#define HWSZ (NH*NW)              // 5776
#define CPB 512                   // cells per block (2 per thread)
#define NBLKX ((HWSZ + CPB - 1) / CPB)   // 12
#define NBLK (NBLKX * NB * NA)    // 576

// scaled anchors = ANCHORS/8, scaled total = TOTAL/8
__constant__ float d_taw[9] = {1.25f,2.0f,4.125f,3.75f,7.75f,7.375f,14.5f,19.5f,46.625f};
__constant__ float d_tah[9] = {1.625f,3.75f,2.875f,7.625f,5.625f,14.875f,11.25f,24.75f,40.75f};
__constant__ float d_saw[3] = {1.25f,2.0f,4.125f};
__constant__ float d_sah[3] = {1.625f,3.75f,2.875f};

__device__ __forceinline__ float safelog(float p) {
    return p > 0.f ? logf(p) : -100.f;   // torch/jax BCE clamp
}
__device__ __forceinline__ float bce(float p, float t) {
    return -(t * safelog(p) + (1.f - t) * safelog(1.f - p));
}
__device__ __forceinline__ float sl1(float p, float t) {
    float d = fabsf(p - t);
    return d < 1.f ? 0.5f * d * d : d - 0.5f;
}
__device__ __forceinline__ float sigmoidf(float z) { return 1.f / (1.f + expf(-z)); }

// Per-cell loss terms for the rare masked path + noobj term.
// Match list is tiny (usually empty); loops over it are wave-uniform skips.
__device__ __forceinline__ void cell_terms(
    bool act, int loff, float x, float y, float zw, float zh, float zc,
    bool ignore, const float (*st)[16], int nm,
    const int* __restrict__ moff, const int* __restrict__ mt,
    const int* __restrict__ mcls, const float* __restrict__ clsbase,
    float* v /* 6 accumulators */)
{
    if (!act) return;
    int tl = -1;
    for (int e = 0; e < nm; e++)
        if (moff[e] == loff) tl = max(tl, mt[e]);      // last scatter wins
    float conf = sigmoidf(zc);
    if (tl >= 0) {
        unsigned long long m0 = 0ull; unsigned m1 = 0u; // tcls OR over all matches
        for (int e = 0; e < nm; e++)
            if (moff[e] == loff) {
                int c = mcls[e];
                if (c < 64) m0 |= 1ull << c; else m1 |= 1u << (c - 64);
            }
        const float* td = st[tl];
        float sc = td[8];
        v[0] += sc * bce(x, td[9]);
        v[1] += sc * bce(y, td[10]);
        v[2] += sc * sl1(zw, td[11]);
        v[3] += sc * sl1(zh, td[12]);
        v[4] += -safelog(conf);                         // bce(conf, 1)
        // 80-class BCE: batch loads 16 at a time so the 23KB-strided gathers
        // overlap (5 vmcnt latency shots instead of 80 serialized round-trips)
        float lcls = 0.f;
        for (int c0 = 0; c0 < NC; c0 += 16) {
            float z[16];
            #pragma unroll
            for (int u = 0; u < 16; u++)
                z[u] = clsbase[(size_t)(c0 + u) * HWSZ];
            #pragma unroll
            for (int u = 0; u < 16; u++) {
                int c = c0 + u;
                float pc = sigmoidf(z[u]);
                float tc = ((c < 64) ? ((m0 >> c) & 1ull) : ((m1 >> (c - 64)) & 1u))
                               ? 1.f : 0.f;
                lcls += bce(pc, tc);
            }
        }
        v[5] += lcls;
    } else if (!ignore) {
        v[4] += 0.5f * (-safelog(1.f - conf));          // 0.5 * bce(conf, 0)
    }
}

// ---------------- kernel 1: per-cell losses, block partials ----------------
__global__ __launch_bounds__(256) void k_main(const float* __restrict__ in,
                                              const float* __restrict__ tg,
                                              float* __restrict__ partials) {
    const int b = blockIdx.y / NA;
    const int a = blockIdx.y % NA;
    const int tid = threadIdx.x;
    const int base = blockIdx.x * CPB;

    // target records: [0..3]=x1,y1,x2,y2  [4]=area(+inf if invalid)
    //                 [8]=scales [9]=tx [10]=ty [11]=tw [12]=th
    __shared__ __align__(16) float st[NT][16];
    __shared__ int s_nm, s_moff[NT], s_mt[NT], s_mcls[NT];
    if (tid == 0) s_nm = 0;
    __syncthreads();
    if (tid < NT) {
        const float* tp = tg + ((size_t)b * NT + tid) * 5;
        float t0 = tp[0], t1 = tp[1], t2 = tp[2], t3 = tp[3], t4 = tp[4];
        bool valid = (t0 + t1 + t2 + t3 + t4) != 0.f;
        float gx = t1 * NW, gy = t2 * NH, gw = t3 * NW, gh = t4 * NH;
        int gi = (int)gx, gj = (int)gy;          // truncation; gx,gy >= 0
        // best of 9 total anchors; first-max wins, matching jnp.argmax
        float best = -1.f; int bn = 0;
        #pragma unroll
        for (int n = 0; n < 9; n++) {
            float inter = fminf(gw, d_taw[n]) * fminf(gh, d_tah[n]);
            float iou = inter / (gw * gh + d_taw[n] * d_tah[n] - inter + 1e-16f);
            if (iou > best) { best = iou; bn = n; }
        }
        int ai = (bn < NA) ? bn : -1;
        bool write = valid && (ai >= 0);
        int aic = (ai < 0) ? 0 : ai;
        float x1 = gx - gw * 0.5f, y1 = gy - gh * 0.5f;
        float x2 = gx + gw * 0.5f, y2 = gy + gh * 0.5f;
        float* o = st[tid];
        o[0] = x1; o[1] = y1; o[2] = x2; o[3] = y2;
        o[4] = valid ? (x2 - x1) * (y2 - y1) : __builtin_inff();
        o[8] = 2.f - t3 * t4;
        o[9] = gx - (float)gi; o[10] = gy - (float)gj;
        o[11] = logf(gw / d_saw[aic] + 1e-16f);
        o[12] = logf(gh / d_sah[aic] + 1e-16f);
        if (write && ai == a) {
            int off = gj * NW + gi - base;
            if (off >= 0 && off < CPB) {
                int slot = atomicAdd(&s_nm, 1);
                s_moff[slot] = off; s_mt[slot] = tid; s_mcls[slot] = (int)t0;
            }
        }
    }
    __syncthreads();

    // two cells per thread: local offsets tid and tid+256
    const int p1 = base + tid, p2 = base + 256 + tid;
    const bool act1 = p1 < HWSZ, act2 = p2 < HWSZ;
    const int q1 = act1 ? p1 : 0, q2 = act2 ? p2 : 0;
    const float* ib = in + (size_t)(b * 255 + a * 85) * HWSZ;

    float zx1 = ib[q1], zy1 = ib[HWSZ + q1], zw1 = ib[2 * HWSZ + q1],
          zh1 = ib[3 * HWSZ + q1], zc1 = ib[4 * HWSZ + q1];
    float zx2 = ib[q2], zy2 = ib[HWSZ + q2], zw2 = ib[2 * HWSZ + q2],
          zh2 = ib[3 * HWSZ + q2], zc2 = ib[4 * HWSZ + q2];

    const int j1 = q1 / NW, i1 = q1 - j1 * NW;
    const int j2 = q2 / NW, i2 = q2 - j2 * NW;
    float x_1 = sigmoidf(zx1), y_1 = sigmoidf(zy1);
    float x_2 = sigmoidf(zx2), y_2 = sigmoidf(zy2);
    float pbx1 = x_1 + (float)i1, pby1 = y_1 + (float)j1;
    float pbx2 = x_2 + (float)i2, pby2 = y_2 + (float)j2;
    float pbw1 = expf(zw1) * d_saw[a], pbh1 = expf(zh1) * d_sah[a];
    float pbw2 = expf(zw2) * d_saw[a], pbh2 = expf(zh2) * d_sah[a];
    float px1a = pbx1 - pbw1 * 0.5f, px1b = pbx1 + pbw1 * 0.5f;
    float py1a = pby1 - pbh1 * 0.5f, py1b = pby1 + pbh1 * 0.5f;
    float px2a = pbx2 - pbw2 * 0.5f, px2b = pbx2 + pbw2 * 0.5f;
    float py2a = pby2 - pbh2 * 0.5f, py2b = pby2 + pbh2 * 0.5f;
    float pa1 = (px1b - px1a) * (py1b - py1a);
    float pa2 = (px2b - px2a) * (py2b - py2a);

    // hot loop: ignore test only; records prefetched 5 at a time into regs
    bool ig1 = false, ig2 = false;
    for (int tb = 0; tb < NT; tb += 5) {
        float4 B[5]; float A_[5];
        #pragma unroll
        for (int u = 0; u < 5; u++) {
            B[u] = *(const float4*)&st[tb + u][0];
            A_[u] = st[tb + u][4];
        }
        #pragma unroll
        for (int u = 0; u < 5; u++) {
            float iw1 = fmaxf(fminf(B[u].z, px1b) - fmaxf(B[u].x, px1a), 0.f);
            float ih1 = fmaxf(fminf(B[u].w, py1b) - fmaxf(B[u].y, py1a), 0.f);
            // iou >= 0.5  <=>  3*inter >= area_t + area_p   (denominator > 0)
            if (3.f * (iw1 * ih1) >= A_[u] + pa1) ig1 = true;
            float iw2 = fmaxf(fminf(B[u].z, px2b) - fmaxf(B[u].x, px2a), 0.f);
            float ih2 = fmaxf(fminf(B[u].w, py2b) - fmaxf(B[u].y, py2a), 0.f);
            if (3.f * (iw2 * ih2) >= A_[u] + pa2) ig2 = true;
        }
    }

    float v[6] = {0.f, 0.f, 0.f, 0.f, 0.f, 0.f};
    const int nm = s_nm;
    cell_terms(act1, tid,       x_1, y_1, zw1, zh1, zc1, ig1, st, nm,
               s_moff, s_mt, s_mcls, ib + 5 * HWSZ + q1, v);
    cell_terms(act2, tid + 256, x_2, y_2, zw2, zh2, zc2, ig2, st, nm,
               s_moff, s_mt, s_mcls, ib + 5 * HWSZ + q2, v);

    // block reduction: wave64 shuffle -> LDS -> 6 plain stores (NO atomics)
    __shared__ float red[4][6];
    const int wid = tid >> 6, lane = tid & 63;
    #pragma unroll
    for (int k = 0; k < 6; k++) {
        float s = v[k];
        #pragma unroll
        for (int off = 32; off > 0; off >>= 1) s += __shfl_down(s, off);
        if (lane == 0) red[wid][k] = s;
    }
    __syncthreads();
    if (tid < 6) {
        const int blk = blockIdx.y * NBLKX + blockIdx.x;
        partials[(size_t)blk * 8 + tid] =
            red[0][tid] + red[1][tid] + red[2][tid] + red[3][tid];
    }
}

// ---------------- kernel 2: reduce partials + n_obj + finalize ----------------
__global__ __launch_bounds__(512) void k_final(const float* __restrict__ tg,
                                               const float* __restrict__ partials,
                                               float* __restrict__ out) {
    const int wid = threadIdx.x >> 6, lane = threadIdx.x & 63;
    __shared__ float rs[8];
    if (wid < 6) {
        float s = 0.f;
        for (int i = lane; i < NBLK; i += 64) s += partials[(size_t)i * 8 + wid];
        #pragma unroll
        for (int off = 32; off > 0; off >>= 1) s += __shfl_down(s, off);
        if (lane == 0) rs[wid] = s;
    } else if (wid == 6) {
        int c = 0;
        for (int i = lane; i < NB * NT; i += 64) {
            const float* tp = tg + (size_t)i * 5;
            if ((tp[0] + tp[1] + tp[2] + tp[3] + tp[4]) != 0.f) c++;
        }
        #pragma unroll
        for (int off = 32; off > 0; off >>= 1) c += __shfl_down(c, off);
        if (lane == 0) rs[6] = (float)c;
    }
    __syncthreads();
    if (threadIdx.x == 0) {
        float n = rs[6];
        float lx = rs[0] / n, ly = rs[1] / n, lw = rs[2] / n, lh = rs[3] / n;
        float lc = rs[4] / n, lcls = rs[5] / n;
        out[0] = 2.5f * (lx + ly) + 2.5f * (lw + lh) + lc + lcls;
        out[1] = lx; out[2] = ly; out[3] = lw; out[4] = lh; out[5] = lc; out[6] = lcls;
    }
}

extern "C" void kernel_launch(void* const* d_in, const int* in_sizes, int n_in,
                              void* d_out, int out_size, void* d_ws, size_t ws_size,
                              hipStream_t stream) {
    const float* input   = (const float*)d_in[0];   // [16,255,76,76] f32
    const float* targets = (const float*)d_in[1];   // [16,50,5] f32
    float* out = (float*)d_out;                     // 7 f32
    float* ws  = (float*)d_ws;                      // block partials: NBLK*8 floats

    dim3 grid(NBLKX, NB * NA);                      // (12, 48)
    k_main<<<grid, 256, 0, stream>>>(input, targets, ws);
    k_final<<<1, 512, 0, stream>>>(targets, ws, out);
}

// Round 5
// 149.167 us; speedup vs baseline: 1.4982x; 1.4982x over previous
//
#include <hip/hip_runtime.h>
#include <cstddef>

// Problem constants (bs=16, T=50, A=3, H=W=76, C=80, stride 8)
#define NB 16
#define NT 50
#define NA 3
#define NH 76
#define NW 76
#define NC 80
#define HWSZ (NH*NW)              // 5776
#define CPB 512                   // cells per block (2 per thread)
#define NBLKX ((HWSZ + CPB - 1) / CPB)   // 12
#define NBLK (NBLKX * NB * NA)    // 576
#define NTARG (NB * NT)           // 800

// scaled anchors = ANCHORS/8, scaled total = TOTAL/8
__constant__ float d_taw[9] = {1.25f,2.0f,4.125f,3.75f,7.75f,7.375f,14.5f,19.5f,46.625f};
__constant__ float d_tah[9] = {1.625f,3.75f,2.875f,7.625f,5.625f,14.875f,11.25f,24.75f,40.75f};
__constant__ float d_saw[3] = {1.25f,2.0f,4.125f};
__constant__ float d_sah[3] = {1.625f,3.75f,2.875f};

__device__ __forceinline__ float safelog(float p) {
    return p > 0.f ? logf(p) : -100.f;   // torch/jax BCE clamp
}
__device__ __forceinline__ float bce(float p, float t) {
    return -(t * safelog(p) + (1.f - t) * safelog(1.f - p));
}
__device__ __forceinline__ float sl1(float p, float t) {
    float d = fabsf(p - t);
    return d < 1.f ? 0.5f * d * d : d - 0.5f;
}
__device__ __forceinline__ float sigmoidf(float z) { return 1.f / (1.f + expf(-z)); }

struct TRec {
    bool valid, write;
    int ai, gi, gj, cls;
    float gx, gy, gw, gh;
};

__device__ __forceinline__ TRec decode(const float* __restrict__ tp) {
    TRec r;
    float t0 = tp[0], t1 = tp[1], t2 = tp[2], t3 = tp[3], t4 = tp[4];
    r.valid = (t0 + t1 + t2 + t3 + t4) != 0.f;
    r.gx = t1 * NW; r.gy = t2 * NH; r.gw = t3 * NW; r.gh = t4 * NH;
    r.gi = (int)r.gx; r.gj = (int)r.gy;       // truncation; gx,gy >= 0
    // best of 9 total anchors (centered -> inter = min(w)*min(h)); first-max wins
    float best = -1.f; int bn = 0;
    #pragma unroll
    for (int n = 0; n < 9; n++) {
        float inter = fminf(r.gw, d_taw[n]) * fminf(r.gh, d_tah[n]);
        float iou = inter / (r.gw * r.gh + d_taw[n] * d_tah[n] - inter + 1e-16f);
        if (iou > best) { best = iou; bn = n; }
    }
    r.ai = (bn < NA) ? bn : -1;
    r.write = r.valid && (r.ai >= 0);
    r.cls = (int)t0;
    return r;
}

// ---------- kernel 1: bulk per-cell work (ignore test + noobj conf term) ----------
__global__ __launch_bounds__(256) void k_main(const float* __restrict__ in,
                                              const float* __restrict__ tg,
                                              float* __restrict__ partials) {
    const int b = blockIdx.y / NA;
    const int a = blockIdx.y % NA;
    const int tid = threadIdx.x;
    const int base = blockIdx.x * CPB;

    __shared__ __align__(16) float st[NT][8];   // [0..3]=x1,y1,x2,y2 [4]=area(+inf invalid)
    __shared__ int s_nm, s_moff[NT];
    if (tid == 0) s_nm = 0;
    __syncthreads();
    if (tid < NT) {
        TRec r = decode(tg + ((size_t)b * NT + tid) * 5);
        float x1 = r.gx - r.gw * 0.5f, y1 = r.gy - r.gh * 0.5f;
        float x2 = r.gx + r.gw * 0.5f, y2 = r.gy + r.gh * 0.5f;
        float* o = st[tid];
        o[0] = x1; o[1] = y1; o[2] = x2; o[3] = y2;
        o[4] = r.valid ? (x2 - x1) * (y2 - y1) : __builtin_inff();
        if (r.write && r.ai == a) {
            int off = r.gj * NW + r.gi - base;
            if (off >= 0 && off < CPB) {
                int slot = atomicAdd(&s_nm, 1);
                s_moff[slot] = off;              // masked cell in this block
            }
        }
    }
    __syncthreads();

    // two cells per thread: local offsets tid and tid+256
    const int p1 = base + tid, p2 = base + 256 + tid;
    const bool act1 = p1 < HWSZ, act2 = p2 < HWSZ;
    const int q1 = act1 ? p1 : 0, q2 = act2 ? p2 : 0;
    const float* ib = in + (size_t)(b * 255 + a * 85) * HWSZ;

    float zx1 = ib[q1], zy1 = ib[HWSZ + q1], zw1 = ib[2 * HWSZ + q1],
          zh1 = ib[3 * HWSZ + q1], zc1 = ib[4 * HWSZ + q1];
    float zx2 = ib[q2], zy2 = ib[HWSZ + q2], zw2 = ib[2 * HWSZ + q2],
          zh2 = ib[3 * HWSZ + q2], zc2 = ib[4 * HWSZ + q2];

    const int j1 = q1 / NW, i1 = q1 - j1 * NW;
    const int j2 = q2 / NW, i2 = q2 - j2 * NW;
    float x_1 = sigmoidf(zx1), y_1 = sigmoidf(zy1);
    float x_2 = sigmoidf(zx2), y_2 = sigmoidf(zy2);
    float pbx1 = x_1 + (float)i1, pby1 = y_1 + (float)j1;
    float pbx2 = x_2 + (float)i2, pby2 = y_2 + (float)j2;
    float pbw1 = expf(zw1) * d_saw[a], pbh1 = expf(zh1) * d_sah[a];
    float pbw2 = expf(zw2) * d_saw[a], pbh2 = expf(zh2) * d_sah[a];
    float px1a = pbx1 - pbw1 * 0.5f, px1b = pbx1 + pbw1 * 0.5f;
    float py1a = pby1 - pbh1 * 0.5f, py1b = pby1 + pbh1 * 0.5f;
    float px2a = pbx2 - pbw2 * 0.5f, px2b = pbx2 + pbw2 * 0.5f;
    float py2a = pby2 - pbh2 * 0.5f, py2b = pby2 + pbh2 * 0.5f;
    float pa1 = (px1b - px1a) * (py1b - py1a);
    float pa2 = (px2b - px2a) * (py2b - py2a);

    // hot loop: ignore test only; records prefetched 5 at a time into regs
    bool ig1 = false, ig2 = false;
    for (int tb = 0; tb < NT; tb += 5) {
        float4 B[5]; float A_[5];
        #pragma unroll
        for (int u = 0; u < 5; u++) {
            B[u] = *(const float4*)&st[tb + u][0];
            A_[u] = st[tb + u][4];
        }
        #pragma unroll
        for (int u = 0; u < 5; u++) {
            float iw1 = fmaxf(fminf(B[u].z, px1b) - fmaxf(B[u].x, px1a), 0.f);
            float ih1 = fmaxf(fminf(B[u].w, py1b) - fmaxf(B[u].y, py1a), 0.f);
            // iou >= 0.5  <=>  3*inter >= area_t + area_p   (denominator > 0)
            if (3.f * (iw1 * ih1) >= A_[u] + pa1) ig1 = true;
            float iw2 = fmaxf(fminf(B[u].z, px2b) - fmaxf(B[u].x, px2a), 0.f);
            float ih2 = fmaxf(fminf(B[u].w, py2b) - fmaxf(B[u].y, py2a), 0.f);
            if (3.f * (iw2 * ih2) >= A_[u] + pa2) ig2 = true;
        }
    }

    // noobj conf term only; masked cells (match list) contribute nothing here
    const int nm = s_nm;                         // wave-uniform
    bool mm1 = false, mm2 = false;
    for (int e = 0; e < nm; e++) {
        int mo = s_moff[e];
        mm1 |= (mo == tid); mm2 |= (mo == tid + 256);
    }
    float lc = 0.f;
    if (act1 && !mm1 && !ig1) lc += 0.5f * (-safelog(1.f - sigmoidf(zc1)));
    if (act2 && !mm2 && !ig2) lc += 0.5f * (-safelog(1.f - sigmoidf(zc2)));

    // block reduction of the single value
    __shared__ float red[4];
    const int wid = tid >> 6, lane = tid & 63;
    float s = lc;
    #pragma unroll
    for (int off = 32; off > 0; off >>= 1) s += __shfl_down(s, off);
    if (lane == 0) red[wid] = s;
    __syncthreads();
    if (tid == 0)
        partials[blockIdx.y * NBLKX + blockIdx.x] = red[0] + red[1] + red[2] + red[3];
}

// ---------- kernel 2: sparse matched-cell losses + reduce + finalize ----------
__global__ __launch_bounds__(512) void k_final(const float* __restrict__ in,
                                               const float* __restrict__ tg,
                                               const float* __restrict__ partials,
                                               float* __restrict__ out) {
    const int tid = threadIdx.x;
    const int wid = tid >> 6, lane = tid & 63;
    __shared__ int s_nmat, s_nobj;
    __shared__ int s_mt[NTARG];
    __shared__ float s_acc[6];
    __shared__ float s_noobj;
    if (tid == 0) { s_nmat = 0; s_nobj = 0; s_noobj = 0.f; }
    if (tid < 6) s_acc[tid] = 0.f;
    __syncthreads();

    // phase B: enumerate write-eligible targets; count valid (n_obj)
    int cval = 0;
    #pragma unroll
    for (int rr = 0; rr < 2; rr++) {
        int idx = tid + rr * 512;
        if (idx < NTARG) {
            TRec tr = decode(tg + (size_t)idx * 5);
            if (tr.valid) cval++;
            if (tr.write) { int slot = atomicAdd(&s_nmat, 1); s_mt[slot] = idx; }
        }
    }
    #pragma unroll
    for (int off = 32; off > 0; off >>= 1) cval += __shfl_down(cval, off);
    if (lane == 0) atomicAdd(&s_nobj, cval);
    __syncthreads();

    // phase C: one wave per matched target; classes parallel across lanes
    const int nmat = s_nmat;
    for (int e = wid; e < nmat; e += 8) {
        const int t = s_mt[e];
        const int b = t / NT, tloc = t - b * NT;
        // lane l decodes target (b, l)
        TRec r; r.valid = false; r.write = false;
        r.ai = -1; r.gi = -1; r.gj = -1; r.cls = 0;
        r.gx = r.gy = r.gw = r.gh = 0.f;
        float txl = 0.f, tyl = 0.f, twl = 0.f, thl = 0.f, scl = 0.f;
        if (lane < NT) {
            r = decode(tg + ((size_t)b * NT + lane) * 5);
            txl = r.gx - (float)r.gi; tyl = r.gy - (float)r.gj;
            int aic = r.ai < 0 ? 0 : r.ai;
            twl = logf(r.gw / d_saw[aic] + 1e-16f);
            thl = logf(r.gh / d_sah[aic] + 1e-16f);
            scl = 2.f - (r.gw / (float)NW) * (r.gh / (float)NH);
        }
        const int a  = __shfl(r.ai, tloc);
        const int gi = __shfl(r.gi, tloc);
        const int gj = __shfl(r.gj, tloc);
        bool match = r.write && (r.ai == a) && (r.gi == gi) && (r.gj == gj);
        unsigned long long mb = __ballot(match);          // nonzero: lane tloc matches
        int tlast = 63 - __clzll((long long)mb);          // last scatter wins
        if (tloc != tlast) continue;                       // another entry owns this cell
        // tcls = OR over all matching targets (each sets its class bit)
        unsigned long long m0 = 0ull; unsigned m1 = 0u;
        unsigned long long mm = mb;
        while (mm) {
            int l = __ffsll(mm) - 1; mm &= mm - 1;
            int c = __shfl(r.cls, l);
            if (c < 64) m0 |= 1ull << c; else m1 |= 1u << (c - 64);
        }
        float tx = __shfl(txl, tlast), ty = __shfl(tyl, tlast);
        float tw = __shfl(twl, tlast), th = __shfl(thl, tlast);
        float sc = __shfl(scl, tlast);
        const size_t cb = ((size_t)b * 255 + (size_t)a * 85) * HWSZ
                        + (size_t)(gj * NW + gi);
        // 5 box/conf logits via lanes 0..4, broadcast
        float z5 = (lane < 5) ? in[cb + (size_t)lane * HWSZ] : 0.f;
        float zx = __shfl(z5, 0), zy = __shfl(z5, 1), zww = __shfl(z5, 2),
              zhh = __shfl(z5, 3), zcf = __shfl(z5, 4);
        // 80 class logits: lane c -> class c; lanes 0..15 also class 64+c
        float zca = in[cb + (size_t)(5 + lane) * HWSZ];
        float zcb = (lane < 16) ? in[cb + (size_t)(69 + lane) * HWSZ] : 0.f;
        float tca = ((m0 >> lane) & 1ull) ? 1.f : 0.f;
        float lcls = bce(sigmoidf(zca), tca);
        if (lane < 16) {
            float tcb = ((m1 >> lane) & 1u) ? 1.f : 0.f;
            lcls += bce(sigmoidf(zcb), tcb);
        }
        #pragma unroll
        for (int off = 32; off > 0; off >>= 1) lcls += __shfl_down(lcls, off);
        if (lane == 0) {
            atomicAdd(&s_acc[0], sc * bce(sigmoidf(zx), tx));
            atomicAdd(&s_acc[1], sc * bce(sigmoidf(zy), ty));
            atomicAdd(&s_acc[2], sc * sl1(zww, tw));
            atomicAdd(&s_acc[3], sc * sl1(zhh, th));
            atomicAdd(&s_acc[4], -safelog(sigmoidf(zcf)));   // bce(conf, 1)
            atomicAdd(&s_acc[5], lcls);
        }
    }

    // phase D: wave 0 reduces the noobj partials
    if (wid == 0) {
        float s = 0.f;
        for (int i = lane; i < NBLK; i += 64) s += partials[i];
        #pragma unroll
        for (int off = 32; off > 0; off >>= 1) s += __shfl_down(s, off);
        if (lane == 0) s_noobj = s;
    }
    __syncthreads();
    if (tid == 0) {
        float n = (float)s_nobj;
        float lx = s_acc[0] / n, ly = s_acc[1] / n;
        float lw = s_acc[2] / n, lh = s_acc[3] / n;
        float lcf = (s_acc[4] + s_noobj) / n, lcl = s_acc[5] / n;
        out[0] = 2.5f * (lx + ly) + 2.5f * (lw + lh) + lcf + lcl;
        out[1] = lx; out[2] = ly; out[3] = lw; out[4] = lh; out[5] = lcf; out[6] = lcl;
    }
}

extern "C" void kernel_launch(void* const* d_in, const int* in_sizes, int n_in,
                              void* d_out, int out_size, void* d_ws, size_t ws_size,
                              hipStream_t stream) {
    const float* input   = (const float*)d_in[0];   // [16,255,76,76] f32
    const float* targets = (const float*)d_in[1];   // [16,50,5] f32
    float* out = (float*)d_out;                     // 7 f32
    float* ws  = (float*)d_ws;                      // noobj partials: NBLK floats

    dim3 grid(NBLKX, NB * NA);                      // (12, 48)
    k_main<<<grid, 256, 0, stream>>>(input, targets, ws);
    k_final<<<1, 512, 0, stream>>>(input, targets, ws, out);
}

// Round 6
// 146.007 us; speedup vs baseline: 1.5306x; 1.0216x over previous
//
#include <hip/hip_runtime.h>
#include <cstddef>

// Problem constants (bs=16, T=50, A=3, H=W=76, C=80, stride 8)
#define NB 16
#define NT 50
#define NA 3
#define NH 76
#define NW 76
#define NC 80
#define HWSZ (NH*NW)              // 5776
#define CPB 1024                  // cells per block (4 per thread)
#define NBLKX ((HWSZ + CPB - 1) / CPB)   // 6
#define NBLK (NBLKX * NB * NA)    // 288 bulk blocks
#define NTARG (NB * NT)           // 800
// ws layout: [0..NBLK) noobj partials; then 6 matched-cell accums; then n_obj
#define WS_ACC  NBLK
#define WS_NOBJ (NBLK + 6)

// scaled anchors = ANCHORS/8, scaled total = TOTAL/8
__constant__ float d_taw[9] = {1.25f,2.0f,4.125f,3.75f,7.75f,7.375f,14.5f,19.5f,46.625f};
__constant__ float d_tah[9] = {1.625f,3.75f,2.875f,7.625f,5.625f,14.875f,11.25f,24.75f,40.75f};
__constant__ float d_saw[3] = {1.25f,2.0f,4.125f};
__constant__ float d_sah[3] = {1.625f,3.75f,2.875f};

__device__ __forceinline__ float safelog(float p) {
    return p > 0.f ? logf(p) : -100.f;   // torch/jax BCE clamp
}
__device__ __forceinline__ float bce(float p, float t) {
    return -(t * safelog(p) + (1.f - t) * safelog(1.f - p));
}
__device__ __forceinline__ float sl1(float p, float t) {
    float d = fabsf(p - t);
    return d < 1.f ? 0.5f * d * d : d - 0.5f;
}
__device__ __forceinline__ float sigmoidf(float z) { return 1.f / (1.f + expf(-z)); }

struct TRec {
    bool valid, write;
    int ai, gi, gj, cls;
    float gx, gy, gw, gh;
};

__device__ __forceinline__ TRec decode(const float* __restrict__ tp) {
    TRec r;
    float t0 = tp[0], t1 = tp[1], t2 = tp[2], t3 = tp[3], t4 = tp[4];
    r.valid = (t0 + t1 + t2 + t3 + t4) != 0.f;
    r.gx = t1 * NW; r.gy = t2 * NH; r.gw = t3 * NW; r.gh = t4 * NH;
    r.gi = (int)r.gx; r.gj = (int)r.gy;       // truncation; gx,gy >= 0
    // best of 9 total anchors (centered -> inter = min(w)*min(h)); first-max wins
    float best = -1.f; int bn = 0;
    #pragma unroll
    for (int n = 0; n < 9; n++) {
        float inter = fminf(r.gw, d_taw[n]) * fminf(r.gh, d_tah[n]);
        float iou = inter / (r.gw * r.gh + d_taw[n] * d_tah[n] - inter + 1e-16f);
        if (iou > best) { best = iou; bn = n; }
    }
    r.ai = (bn < NA) ? bn : -1;
    r.write = r.valid && (r.ai >= 0);
    r.cls = (int)t0;
    return r;
}

// ---------- kernel 1: bulk per-cell work + one concurrent sparse block ----------
__global__ __launch_bounds__(256) void k_main(const float* __restrict__ in,
                                              const float* __restrict__ tg,
                                              float* __restrict__ ws) {
    const int tid = threadIdx.x;
    const int wid = tid >> 6, lane = tid & 63;

    // bulk path shared
    __shared__ __align__(16) float st[NT][8];  // [0..3]=x1,y1,x2,y2 [4]=area(+inf invalid)
    __shared__ int s_nm, s_moff[NT];
    __shared__ float red[4];
    // sparse path shared
    __shared__ int s_nmat, s_nobj;
    __shared__ int s_mt[NTARG];
    __shared__ float s_acc[6];

    if (blockIdx.y == NB * NA) {
        // ======== sparse block: matched-cell losses + n_obj ========
        if (blockIdx.x != 0) return;           // only one sparse block does work
        if (tid == 0) { s_nmat = 0; s_nobj = 0; }
        if (tid < 6) s_acc[tid] = 0.f;
        __syncthreads();

        int cval = 0;
        #pragma unroll
        for (int rr = 0; rr < 4; rr++) {
            int idx = tid + rr * 256;
            if (idx < NTARG) {
                TRec tr = decode(tg + (size_t)idx * 5);
                if (tr.valid) cval++;
                if (tr.write) { int slot = atomicAdd(&s_nmat, 1); s_mt[slot] = idx; }
            }
        }
        #pragma unroll
        for (int off = 32; off > 0; off >>= 1) cval += __shfl_down(cval, off);
        if (lane == 0) atomicAdd(&s_nobj, cval);
        __syncthreads();

        const int nmat = s_nmat;
        for (int e = wid; e < nmat; e += 4) {  // one wave per matched target
            const int t = s_mt[e];
            const int b = t / NT, tloc = t - b * NT;
            TRec r; r.valid = false; r.write = false;
            r.ai = -1; r.gi = -1; r.gj = -1; r.cls = 0;
            r.gx = r.gy = r.gw = r.gh = 0.f;
            float txl = 0.f, tyl = 0.f, twl = 0.f, thl = 0.f, scl = 0.f;
            if (lane < NT) {
                r = decode(tg + ((size_t)b * NT + lane) * 5);
                txl = r.gx - (float)r.gi; tyl = r.gy - (float)r.gj;
                int aic = r.ai < 0 ? 0 : r.ai;
                twl = logf(r.gw / d_saw[aic] + 1e-16f);
                thl = logf(r.gh / d_sah[aic] + 1e-16f);
                scl = 2.f - (r.gw / (float)NW) * (r.gh / (float)NH);
            }
            const int a  = __shfl(r.ai, tloc);
            const int gi = __shfl(r.gi, tloc);
            const int gj = __shfl(r.gj, tloc);
            bool match = r.write && (r.ai == a) && (r.gi == gi) && (r.gj == gj);
            unsigned long long mb = __ballot(match);      // lane tloc is set
            int tlast = 63 - __clzll((long long)mb);      // last scatter wins
            if (tloc != tlast) continue;                  // another entry owns cell
            // tcls = OR over all matching targets
            unsigned long long m0 = 0ull; unsigned m1 = 0u;
            unsigned long long mm = mb;
            while (mm) {
                int l = __ffsll(mm) - 1; mm &= mm - 1;
                int c = __shfl(r.cls, l);
                if (c < 64) m0 |= 1ull << c; else m1 |= 1u << (c - 64);
            }
            float tx = __shfl(txl, tlast), ty = __shfl(tyl, tlast);
            float tw = __shfl(twl, tlast), th = __shfl(thl, tlast);
            float sc = __shfl(scl, tlast);
            const size_t cb = ((size_t)b * 255 + (size_t)a * 85) * HWSZ
                            + (size_t)(gj * NW + gi);
            float z5 = (lane < 5) ? in[cb + (size_t)lane * HWSZ] : 0.f;
            float zx = __shfl(z5, 0), zy = __shfl(z5, 1), zww = __shfl(z5, 2),
                  zhh = __shfl(z5, 3), zcf = __shfl(z5, 4);
            float zca = in[cb + (size_t)(5 + lane) * HWSZ];       // classes 0..63
            float zcb = (lane < 16) ? in[cb + (size_t)(69 + lane) * HWSZ] : 0.f;
            float tca = ((m0 >> lane) & 1ull) ? 1.f : 0.f;
            float lcls = bce(sigmoidf(zca), tca);
            if (lane < 16) {
                float tcb = ((m1 >> lane) & 1u) ? 1.f : 0.f;
                lcls += bce(sigmoidf(zcb), tcb);
            }
            #pragma unroll
            for (int off = 32; off > 0; off >>= 1) lcls += __shfl_down(lcls, off);
            if (lane == 0) {
                atomicAdd(&s_acc[0], sc * bce(sigmoidf(zx), tx));
                atomicAdd(&s_acc[1], sc * bce(sigmoidf(zy), ty));
                atomicAdd(&s_acc[2], sc * sl1(zww, tw));
                atomicAdd(&s_acc[3], sc * sl1(zhh, th));
                atomicAdd(&s_acc[4], -safelog(sigmoidf(zcf)));    // bce(conf,1)
                atomicAdd(&s_acc[5], lcls);
            }
        }
        __syncthreads();
        if (tid < 6) ws[WS_ACC + tid] = s_acc[tid];
        if (tid == 6) ws[WS_NOBJ] = (float)s_nobj;
        return;
    }

    // ======== bulk path: ignore test + noobj conf term, 4 cells/thread ========
    const int b = blockIdx.y / NA;
    const int a = blockIdx.y % NA;
    const int base = blockIdx.x * CPB;

    if (tid == 0) s_nm = 0;
    __syncthreads();
    if (tid < NT) {
        TRec r = decode(tg + ((size_t)b * NT + tid) * 5);
        float x1 = r.gx - r.gw * 0.5f, y1 = r.gy - r.gh * 0.5f;
        float x2 = r.gx + r.gw * 0.5f, y2 = r.gy + r.gh * 0.5f;
        float* o = st[tid];
        o[0] = x1; o[1] = y1; o[2] = x2; o[3] = y2;
        o[4] = r.valid ? (x2 - x1) * (y2 - y1) : __builtin_inff();
        if (r.write && r.ai == a) {
            int off = r.gj * NW + r.gi - base;
            if (off >= 0 && off < CPB) {
                int slot = atomicAdd(&s_nm, 1);
                s_moff[slot] = off;              // masked cell in this block
            }
        }
    }
    __syncthreads();

    const float* ib = in + (size_t)(b * 255 + a * 85) * HWSZ;
    bool act[4]; int q[4];
    float zc[4], pxa[4], pxb[4], pya[4], pyb[4], pa[4];
    #pragma unroll
    for (int c = 0; c < 4; c++) {
        int p = base + c * 256 + tid;
        act[c] = p < HWSZ;
        q[c] = act[c] ? p : 0;
        float zx = ib[q[c]], zy = ib[HWSZ + q[c]], zw = ib[2 * HWSZ + q[c]],
              zh = ib[3 * HWSZ + q[c]];
        zc[c] = ib[4 * HWSZ + q[c]];
        int j = q[c] / NW, i = q[c] - j * NW;
        float x = sigmoidf(zx), y = sigmoidf(zy);
        float pbx = x + (float)i, pby = y + (float)j;
        float pbw = expf(zw) * d_saw[a], pbh = expf(zh) * d_sah[a];
        pxa[c] = pbx - pbw * 0.5f; pxb[c] = pbx + pbw * 0.5f;
        pya[c] = pby - pbh * 0.5f; pyb[c] = pby + pbh * 0.5f;
        pa[c] = (pxb[c] - pxa[c]) * (pyb[c] - pya[c]);
    }

    bool ig[4] = {false, false, false, false};
    for (int tb = 0; tb < NT; tb += 5) {
        float4 B[5]; float A_[5];
        #pragma unroll
        for (int u = 0; u < 5; u++) {
            B[u] = *(const float4*)&st[tb + u][0];
            A_[u] = st[tb + u][4];
        }
        #pragma unroll
        for (int u = 0; u < 5; u++) {
            #pragma unroll
            for (int c = 0; c < 4; c++) {
                float iw = fmaxf(fminf(B[u].z, pxb[c]) - fmaxf(B[u].x, pxa[c]), 0.f);
                float ih = fmaxf(fminf(B[u].w, pyb[c]) - fmaxf(B[u].y, pya[c]), 0.f);
                // iou >= 0.5  <=>  3*inter >= area_t + area_p  (denominator > 0)
                if (3.f * (iw * ih) >= A_[u] + pa[c]) ig[c] = true;
            }
        }
    }

    // noobj conf term; masked cells contribute nothing here
    const int nm = s_nm;                         // wave-uniform
    bool mm[4] = {false, false, false, false};
    for (int e = 0; e < nm; e++) {
        int mo = s_moff[e];
        #pragma unroll
        for (int c = 0; c < 4; c++) mm[c] |= (mo == c * 256 + tid);
    }
    float lc = 0.f;
    #pragma unroll
    for (int c = 0; c < 4; c++)
        if (act[c] && !mm[c] && !ig[c]) lc += 0.5f * (-safelog(1.f - sigmoidf(zc[c])));

    float s = lc;
    #pragma unroll
    for (int off = 32; off > 0; off >>= 1) s += __shfl_down(s, off);
    if (lane == 0) red[wid] = s;
    __syncthreads();
    if (tid == 0)
        ws[blockIdx.y * NBLKX + blockIdx.x] = red[0] + red[1] + red[2] + red[3];
}

// ---------- kernel 2: tiny reduce + finalize ----------
__global__ __launch_bounds__(64) void k_final(const float* __restrict__ ws,
                                              float* __restrict__ out) {
    const int lane = threadIdx.x;
    float s = 0.f;
    for (int i = lane; i < NBLK; i += 64) s += ws[i];
    #pragma unroll
    for (int off = 32; off > 0; off >>= 1) s += __shfl_down(s, off);
    if (lane == 0) {
        float n = ws[WS_NOBJ];
        float lx = ws[WS_ACC + 0] / n, ly = ws[WS_ACC + 1] / n;
        float lw = ws[WS_ACC + 2] / n, lh = ws[WS_ACC + 3] / n;
        float lcf = (ws[WS_ACC + 4] + s) / n, lcl = ws[WS_ACC + 5] / n;
        out[0] = 2.5f * (lx + ly) + 2.5f * (lw + lh) + lcf + lcl;
        out[1] = lx; out[2] = ly; out[3] = lw; out[4] = lh; out[5] = lcf; out[6] = lcl;
    }
}

extern "C" void kernel_launch(void* const* d_in, const int* in_sizes, int n_in,
                              void* d_out, int out_size, void* d_ws, size_t ws_size,
                              hipStream_t stream) {
    const float* input   = (const float*)d_in[0];   // [16,255,76,76] f32
    const float* targets = (const float*)d_in[1];   // [16,50,5] f32
    float* out = (float*)d_out;                     // 7 f32
    float* ws  = (float*)d_ws;

    dim3 grid(NBLKX, NB * NA + 1);                  // (6, 49): y==48 -> sparse block
    k_main<<<grid, 256, 0, stream>>>(input, targets, ws);
    k_final<<<1, 64, 0, stream>>>(ws, out);
}